// Round 17
// baseline (123.077 us; speedup 1.0000x reference)
//
#include <hip/hip_runtime.h>

// GPDGaussian: per-pixel 629x3 conv -> (m, S=R^T diag(s) R, s)
// r17 ONE-WAVE BLOCKS, FINE-GRAINED DRAIN. Diagnosis r5-r16: every config had
// grid-supply/residency ~1.1 -> two sequential batch-waves -> realized
// occupancy pinned at ~8.6 waves/CU and dur at ~84us. 1-wave blocks (64 thr,
// 3 px, 5462 blocks) finish independently -> continuous backfill at the
// 16-WG/CU cap. Zero __syncthreads (wave-private LDS, lgkmcnt ordering);
// launch_bounds(64,4) + sched fences prevent r7's spill failure.

#define CCH 34
#define ACH 561
#define HWPIX 4096
#define NPIX 16384
#define PXB 3                   // pixels per block
#define TPP 17                  // threads per pixel
#define NTHR 64                 // 51 active in B/C
#define CSPX (141 * 8)          // cs bytes per px per chunk = 1128
#define VROW 35                 // V pair-row stride in dwords (140B, odd->banks ok)
#define VPX (17 * VROW * 4)     // 2380 B per-pixel V region
#define OFF_S 557056
#define OFF_s 19496960
#define LOG2E 1.4426950408889634f

typedef float    f32x2 __attribute__((ext_vector_type(2)));
typedef _Float16 h2    __attribute__((ext_vector_type(2)));

struct PairsT {
    short i[ACH]; short j[ACH];
    constexpr PairsT() : i(), j() {
        int p = 0;
        for (int a = 0; a < CCH - 1; ++a)
            for (int b = a + 1; b < CCH; ++b) { i[p] = (short)a; j[p] = (short)b; ++p; }
    }
};
__device__ constexpr PairsT PR{};

__device__ __forceinline__ float dot2h(h2 a, h2 b, float c) {
#if __has_builtin(__builtin_amdgcn_fdot2)
    return __builtin_amdgcn_fdot2(a, b, c, false);
#else
    return fmaf((float)a[0], (float)b[0], fmaf((float)a[1], (float)b[1], c));
#endif
}

// Givens rotation on packed row-pair: Ri' = c*Ri + s*Rj ; Rj' = c*Rj - s*Ri
__device__ __forceinline__ void rot2(f32x2& Ri, f32x2& Rj, f32x2 c2, f32x2 s2) {
    f32x2 t1 = s2 * Rj;
    f32x2 t2 = s2 * Ri;
    Ri = __builtin_elementwise_fma(c2, Ri, t1);
    Rj = __builtin_elementwise_fma(c2, Rj, -t2);
}

template <int P0, int P1>
__device__ __forceinline__ void apply_rots(f32x2* R2, const char* csb) {
    #pragma unroll
    for (int k = P0; k < P1; ++k) {
        f32x2 cell = *(const f32x2*)(csb + (k - P0) * 8);   // {c,s} b64 broadcast
        f32x2 c2 = __builtin_shufflevector(cell, cell, 0, 0);
        f32x2 s2 = __builtin_shufflevector(cell, cell, 1, 1);
        rot2(R2[PR.i[k]], R2[PR.j[k]], c2, s2);
    }
}

__device__ __forceinline__ float2 cs_of(float wv) {
    // angle = pi*tanh(wv); HW cos/sin take revolutions: tanh(wv)/2
    float e  = __builtin_amdgcn_exp2f((2.0f * LOG2E) * wv);
    float tt = 1.0f - 2.0f * __builtin_amdgcn_rcpf(e + 1.0f);
    float rv = 0.5f * tt;
    return make_float2(__builtin_amdgcn_cosf(rv), __builtin_amdgcn_sinf(rv));
}

// one task = one pixel's angle l -> 8B {c,s} write
template <int G0, int LEN>
__device__ __forceinline__ void fill_cs(const float* __restrict__ Wm,
                                        const float* __restrict__ bvec,
                                        const float* xs, char* csbuf,
                                        int npx, int t) {
    for (int o = t; o < npx * LEN; o += NTHR) {
        int px = (int)((unsigned)o / (unsigned)LEN);
        int l  = o - px * LEN;
        int ch = 2 * CCH + G0 + l;
        float wv = fmaf(Wm[ch*3+0], xs[px*3+0],
                   fmaf(Wm[ch*3+1], xs[px*3+1], Wm[ch*3+2] * xs[px*3+2])) + bvec[ch];
        *(float2*)(csbuf + px * CSPX + l * 8) = cs_of(wv);
    }
}

__global__ __launch_bounds__(NTHR, 4) void gpd_kernel(
    const float* __restrict__ x,     // (4,3,64,64)
    const float* __restrict__ Wm,    // (629,3)
    const float* __restrict__ bvec,  // (629,)
    float* __restrict__ out)
{
    __shared__ alignas(16) char vbuf[PXB * VPX];   // 7140 B (cs 3384 overlays)
    __shared__ _Float16 lds_sh[PXB * CCH];         // s in f16
    __shared__ float xs[PXB * 3];

    const int t   = threadIdx.x;                   // == lane (1-wave block)
    const int p0  = blockIdx.x * PXB;
    const int npx = min(PXB, NPIX - p0);

    // ---- stage x into LDS ----
    for (int i = t; i < npx * 3; i += NTHR) {
        int px = (int)((unsigned)i / 3u); int c = i - px * 3;
        int p = p0 + px; int b = p >> 12; int hw = p & 4095;
        xs[i] = x[(b * 3 + c) * HWPIX + hw];
    }

    // ---- A: mean + s channels ----
    for (int o = t; o < npx * 68; o += NTHR) {
        int q = (int)((unsigned)o / 68u); int ch = o - q * 68;
        int p = p0 + q; int b = p >> 12; int hw = p & 4095;
        float wv = fmaf(Wm[ch*3+0], xs[q*3+0],
                   fmaf(Wm[ch*3+1], xs[q*3+1], Wm[ch*3+2] * xs[q*3+2])) + bvec[ch];
        if (ch < CCH) {
            out[(size_t)p * CCH + ch] = wv;                       // mean
        } else {
            float e  = __builtin_amdgcn_exp2f(-wv * LOG2E);
            float sg = __builtin_amdgcn_rcpf(1.0f + e);
            float sv = fmaf(999.999f, sg, 0.001f);                // s
            int c = ch - CCH;
            out[OFF_s + (size_t)(b * CCH + c) * HWPIX + hw] = sv;
            lds_sh[q * CCH + c] = (_Float16)sv;
        }
    }

    const int px = t / TPP;                  // pixel owned (0..2; t>=51 -> 3)
    const int u  = t - px * TPP;             // row-pair index: rows (2u, 2u+1)
    const bool act = (px < npx) && (px < PXB);
    const char* csb = vbuf + px * CSPX;

    f32x2 R2[CCH];                           // R2[n] = {R[2u][n], R[2u+1][n]}
    #pragma unroll
    for (int n = 0; n < CCH; ++n) {
        R2[n][0] = (n == 2 * u)     ? 1.0f : 0.0f;
        R2[n][1] = (n == 2 * u + 1) ? 1.0f : 0.0f;
    }

    // ---- 4 chunks: fill cos/sin -> rotate (wave-private; fences keep the
    //      fill's transcendental temps from inflating rot-phase pressure) ----
    __builtin_amdgcn_sched_barrier(0);
    fill_cs<0, 141>(Wm, bvec, xs, vbuf, npx, t);
    __builtin_amdgcn_sched_barrier(0);
    if (act) apply_rots<0, 141>(R2, csb);
    __builtin_amdgcn_sched_barrier(0);
    fill_cs<141, 140>(Wm, bvec, xs, vbuf, npx, t);
    __builtin_amdgcn_sched_barrier(0);
    if (act) apply_rots<141, 281>(R2, csb);
    __builtin_amdgcn_sched_barrier(0);
    fill_cs<281, 140>(Wm, bvec, xs, vbuf, npx, t);
    __builtin_amdgcn_sched_barrier(0);
    if (act) apply_rots<281, 421>(R2, csb);
    __builtin_amdgcn_sched_barrier(0);
    fill_cs<421, 140>(Wm, bvec, xs, vbuf, npx, t);
    __builtin_amdgcn_sched_barrier(0);
    if (act) apply_rots<421, 561>(R2, csb);
    __builtin_amdgcn_sched_barrier(0);

    // ---- V write: cvt_pkrtz(R2[n]) IS the f16 row-pair dword [u][n] ----
    if (act) {
        unsigned* vb = (unsigned*)(vbuf + px * VPX) + u * VROW;
        #pragma unroll
        for (int n = 0; n < CCH; ++n)
            vb[n] = __builtin_bit_cast(unsigned,
                        __builtin_amdgcn_cvt_pkrtz(R2[n][0], R2[n][1]));
    }
    __builtin_amdgcn_sched_barrier(0);

    // ---- phase C: S rows 2u and 2u+1 in ONE pass (shared rr reads) ----
    if (act) {
        const unsigned* vb = (const unsigned*)(vbuf + px * VPX);
        const _Float16* sh = lds_sh + px * CCH;
        float aL[CCH], aH[CCH];
        #pragma unroll
        for (int n = 0; n < CCH; ++n) { aL[n] = 0.0f; aH[n] = 0.0f; }
        for (int mp = 0; mp < 17; ++mp) {
            const unsigned* row = vb + mp * VROW;
            h2 sh2 = *(const h2*)(sh + 2 * mp);
            h2 vkL = __builtin_bit_cast(h2, row[2 * u])     * sh2;
            h2 vkH = __builtin_bit_cast(h2, row[2 * u + 1]) * sh2;
            #pragma unroll
            for (int g = 0; g < 8; ++g) {
                uint4 rr = *(const uint4*)(row + 4 * g);
                h2 r0 = __builtin_bit_cast(h2, rr.x), r1 = __builtin_bit_cast(h2, rr.y);
                h2 r2 = __builtin_bit_cast(h2, rr.z), r3 = __builtin_bit_cast(h2, rr.w);
                aL[4*g+0] = dot2h(vkL, r0, aL[4*g+0]);  aH[4*g+0] = dot2h(vkH, r0, aH[4*g+0]);
                aL[4*g+1] = dot2h(vkL, r1, aL[4*g+1]);  aH[4*g+1] = dot2h(vkH, r1, aH[4*g+1]);
                aL[4*g+2] = dot2h(vkL, r2, aL[4*g+2]);  aH[4*g+2] = dot2h(vkH, r2, aH[4*g+2]);
                aL[4*g+3] = dot2h(vkL, r3, aL[4*g+3]);  aH[4*g+3] = dot2h(vkH, r3, aH[4*g+3]);
            }
            uint2 rr2 = *(const uint2*)(row + 32);
            h2 r32 = __builtin_bit_cast(h2, rr2.x), r33 = __builtin_bit_cast(h2, rr2.y);
            aL[32] = dot2h(vkL, r32, aL[32]);  aH[32] = dot2h(vkH, r32, aH[32]);
            aL[33] = dot2h(vkL, r33, aL[33]);  aH[33] = dot2h(vkH, r33, aH[33]);
        }
        // write rows 2u,2u+1 = 68 contiguous floats = 17 aligned float4
        float* os = out + OFF_S + (size_t)(p0 + px) * (CCH * CCH) + 2 * u * CCH;
        #pragma unroll
        for (int q = 0; q < 17; ++q) {
            float4 v;
            v.x = (4*q+0 < 34) ? aL[4*q+0] : aH[4*q+0-34];
            v.y = (4*q+1 < 34) ? aL[4*q+1] : aH[4*q+1-34];
            v.z = (4*q+2 < 34) ? aL[4*q+2] : aH[4*q+2-34];
            v.w = (4*q+3 < 34) ? aL[4*q+3] : aH[4*q+3-34];
            *(float4*)(os + 4 * q) = v;
        }
    }
}

extern "C" void kernel_launch(void* const* d_in, const int* in_sizes, int n_in,
                              void* d_out, int out_size, void* d_ws, size_t ws_size,
                              hipStream_t stream) {
    const float* x  = (const float*)d_in[0];
    const float* W  = (const float*)d_in[1];
    const float* bv = (const float*)d_in[2];
    float* out = (float*)d_out;
    const int nblk = (NPIX + PXB - 1) / PXB;   // 5462
    hipLaunchKernelGGL(gpd_kernel, dim3(nblk), dim3(NTHR), 0, stream,
                       x, W, bv, out);
}

// Round 18
// 78.658 us; speedup vs baseline: 1.5647x; 1.5647x over previous
//
#include <hip/hip_runtime.h>

// GPDGaussian: per-pixel 629x3 conv -> (m, S=R^T diag(s) R, s)
// r18 = r13 + SPLIT-V phase C. Fitting r2-r17: effective concurrent-LDS
// budget is ~80KB/CU (every config realized 75-80KB resident), and at
// 2.45KB LDS/px (whole 34x34 f16 V staged) that pins residency at ~8.6
// waves/CU -> 2.2/SIMD -> chain-bound 50% VALUBusy -> the 84us attractor.
// Fix: stage V in TWO half-passes (pair-rows 0-8, then 9-16) into a 9-row
// region; S accumulators persist in registers. LDS/px 2448->1296B, block
// 9.7KB -> 8 blocks x 2 waves = 16 waves/CU inside 80KB.

#define CCH 34
#define ACH 561
#define HWPIX 4096
#define NPIX 16384
#define PXB 7                   // pixels per block
#define TPP 17                  // threads per pixel
#define NTHR 128                // 119 active in B/C
#define CSPX (141 * 8)          // cs bytes per px per chunk = 1128 (<= VHPX)
#define VROW 36                 // V pair-row stride in dwords (144B, 16B-aligned)
#define VHPX (9 * VROW * 4)     // 1296 B per-pixel HALF-V region
#define OFF_S 557056
#define OFF_s 19496960
#define LOG2E 1.4426950408889634f

typedef float    f32x2 __attribute__((ext_vector_type(2)));
typedef _Float16 h2    __attribute__((ext_vector_type(2)));

struct PairsT {
    short i[ACH]; short j[ACH];
    constexpr PairsT() : i(), j() {
        int p = 0;
        for (int a = 0; a < CCH - 1; ++a)
            for (int b = a + 1; b < CCH; ++b) { i[p] = (short)a; j[p] = (short)b; ++p; }
    }
};
__device__ constexpr PairsT PR{};

__device__ __forceinline__ float dot2h(h2 a, h2 b, float c) {
#if __has_builtin(__builtin_amdgcn_fdot2)
    return __builtin_amdgcn_fdot2(a, b, c, false);
#else
    return fmaf((float)a[0], (float)b[0], fmaf((float)a[1], (float)b[1], c));
#endif
}

// Givens rotation on packed row-pair: Ri' = c*Ri + s*Rj ; Rj' = c*Rj - s*Ri
__device__ __forceinline__ void rot2(f32x2& Ri, f32x2& Rj, f32x2 c2, f32x2 s2) {
    f32x2 t1 = s2 * Rj;
    f32x2 t2 = s2 * Ri;
    Ri = __builtin_elementwise_fma(c2, Ri, t1);
    Rj = __builtin_elementwise_fma(c2, Rj, -t2);
}

template <int P0, int P1>
__device__ __forceinline__ void apply_rots(f32x2* R2, const char* csb) {
    #pragma unroll
    for (int k = P0; k < P1; ++k) {
        f32x2 cell = *(const f32x2*)(csb + (k - P0) * 8);   // {c,s} b64 read
        f32x2 c2 = __builtin_shufflevector(cell, cell, 0, 0);
        f32x2 s2 = __builtin_shufflevector(cell, cell, 1, 1);
        rot2(R2[PR.i[k]], R2[PR.j[k]], c2, s2);
    }
}

__device__ __forceinline__ float2 cs_of(float wv) {
    // angle = pi*tanh(wv); HW cos/sin take revolutions: tanh(wv)/2
    float e  = __builtin_amdgcn_exp2f((2.0f * LOG2E) * wv);
    float tt = 1.0f - 2.0f * __builtin_amdgcn_rcpf(e + 1.0f);
    float rv = 0.5f * tt;
    return make_float2(__builtin_amdgcn_cosf(rv), __builtin_amdgcn_sinf(rv));
}

// one task = one pixel's angle l -> 8B {c,s} write
template <int G0, int LEN>
__device__ __forceinline__ void fill_cs(const float* __restrict__ Wm,
                                        const float* __restrict__ bvec,
                                        const float* xs, char* csbuf,
                                        int npx, int t) {
    for (int o = t; o < npx * LEN; o += NTHR) {
        int px = (int)((unsigned)o / (unsigned)LEN);
        int l  = o - px * LEN;
        int ch = 2 * CCH + G0 + l;
        float wv = fmaf(Wm[ch*3+0], xs[px*3+0],
                   fmaf(Wm[ch*3+1], xs[px*3+1], Wm[ch*3+2] * xs[px*3+2])) + bvec[ch];
        *(float2*)(csbuf + px * CSPX + l * 8) = cs_of(wv);
    }
}

// accumulate S contributions from staged pair-rows [GOFF, GOFF+NMP)
template <int GOFF, int NMP>
__device__ __forceinline__ void accum_pass(const unsigned* vb, const _Float16* sh,
                                           int u, float* aL, float* aH) {
    for (int mp = 0; mp < NMP; ++mp) {
        const unsigned* row = vb + mp * VROW;
        h2 sh2 = *(const h2*)(sh + 2 * (GOFF + mp));
        h2 vkL = __builtin_bit_cast(h2, row[2 * u])     * sh2;
        h2 vkH = __builtin_bit_cast(h2, row[2 * u + 1]) * sh2;
        #pragma unroll
        for (int g = 0; g < 8; ++g) {
            uint4 rr = *(const uint4*)(row + 4 * g);
            h2 r0 = __builtin_bit_cast(h2, rr.x), r1 = __builtin_bit_cast(h2, rr.y);
            h2 r2 = __builtin_bit_cast(h2, rr.z), r3 = __builtin_bit_cast(h2, rr.w);
            aL[4*g+0] = dot2h(vkL, r0, aL[4*g+0]);  aH[4*g+0] = dot2h(vkH, r0, aH[4*g+0]);
            aL[4*g+1] = dot2h(vkL, r1, aL[4*g+1]);  aH[4*g+1] = dot2h(vkH, r1, aH[4*g+1]);
            aL[4*g+2] = dot2h(vkL, r2, aL[4*g+2]);  aH[4*g+2] = dot2h(vkH, r2, aH[4*g+2]);
            aL[4*g+3] = dot2h(vkL, r3, aL[4*g+3]);  aH[4*g+3] = dot2h(vkH, r3, aH[4*g+3]);
        }
        uint2 rr2 = *(const uint2*)(row + 32);
        h2 r32 = __builtin_bit_cast(h2, rr2.x), r33 = __builtin_bit_cast(h2, rr2.y);
        aL[32] = dot2h(vkL, r32, aL[32]);  aH[32] = dot2h(vkH, r32, aH[32]);
        aL[33] = dot2h(vkL, r33, aL[33]);  aH[33] = dot2h(vkH, r33, aH[33]);
    }
}

__global__ __launch_bounds__(NTHR, 4) void gpd_kernel(
    const float* __restrict__ x,     // (4,3,64,64)
    const float* __restrict__ Wm,    // (629,3)
    const float* __restrict__ bvec,  // (629,)
    float* __restrict__ out)
{
    __shared__ alignas(16) char vbuf[PXB * VHPX];  // 9072 B (cs 7896 overlays)
    __shared__ _Float16 lds_sh[PXB * CCH];         // s in f16 (476 B)
    __shared__ float xs[PXB * 3];                  // 84 B

    const int t   = threadIdx.x;
    const int p0  = blockIdx.x * PXB;
    const int npx = min(PXB, NPIX - p0);

    // ---- stage x into LDS ----
    for (int i = t; i < npx * 3; i += NTHR) {
        int px = (int)((unsigned)i / 3u); int c = i - px * 3;
        int p = p0 + px; int b = p >> 12; int hw = p & 4095;
        xs[i] = x[(b * 3 + c) * HWPIX + hw];
    }
    __syncthreads();

    // ---- A: mean + s channels ----
    for (int o = t; o < npx * 68; o += NTHR) {
        int q = (int)((unsigned)o / 68u); int ch = o - q * 68;
        int p = p0 + q; int b = p >> 12; int hw = p & 4095;
        float wv = fmaf(Wm[ch*3+0], xs[q*3+0],
                   fmaf(Wm[ch*3+1], xs[q*3+1], Wm[ch*3+2] * xs[q*3+2])) + bvec[ch];
        if (ch < CCH) {
            out[(size_t)p * CCH + ch] = wv;                       // mean
        } else {
            float e  = __builtin_amdgcn_exp2f(-wv * LOG2E);
            float sg = __builtin_amdgcn_rcpf(1.0f + e);
            float sv = fmaf(999.999f, sg, 0.001f);                // s
            int c = ch - CCH;
            out[OFF_s + (size_t)(b * CCH + c) * HWPIX + hw] = sv;
            lds_sh[q * CCH + c] = (_Float16)sv;
        }
    }

    const int px = t / TPP;                  // pixel owned (0..6; t>=119 -> 7)
    const int u  = t - px * TPP;             // row-pair index: rows (2u, 2u+1)
    const bool act = (px < npx) && (px < PXB);
    const char* csb = vbuf + px * CSPX;

    f32x2 R2[CCH];                           // R2[n] = {R[2u][n], R[2u+1][n]}
    #pragma unroll
    for (int n = 0; n < CCH; ++n) {
        R2[n][0] = (n == 2 * u)     ? 1.0f : 0.0f;
        R2[n][1] = (n == 2 * u + 1) ? 1.0f : 0.0f;
    }

    // ---- 4 chunks: fill cos/sin -> rotate ----
    fill_cs<0, 141>(Wm, bvec, xs, vbuf, npx, t);
    __syncthreads();
    if (act) apply_rots<0, 141>(R2, csb);
    __syncthreads();
    fill_cs<141, 140>(Wm, bvec, xs, vbuf, npx, t);
    __syncthreads();
    if (act) apply_rots<141, 281>(R2, csb);
    __syncthreads();
    fill_cs<281, 140>(Wm, bvec, xs, vbuf, npx, t);
    __syncthreads();
    if (act) apply_rots<281, 421>(R2, csb);
    __syncthreads();
    fill_cs<421, 140>(Wm, bvec, xs, vbuf, npx, t);
    __syncthreads();
    if (act) apply_rots<421, 561>(R2, csb);
    __syncthreads();                         // all cs reads done; V overlays

    // ---- pack this thread's pair-row to f16 dwords; R2 dies ----
    unsigned rh[CCH];
    #pragma unroll
    for (int n = 0; n < CCH; ++n)
        rh[n] = __builtin_bit_cast(unsigned,
                    __builtin_amdgcn_cvt_pkrtz(R2[n][0], R2[n][1]));

    unsigned* vreg = (unsigned*)(vbuf + px * VHPX);
    const _Float16* sh = lds_sh + px * CCH;
    float aL[CCH], aH[CCH];
    #pragma unroll
    for (int n = 0; n < CCH; ++n) { aL[n] = 0.0f; aH[n] = 0.0f; }

    // ---- phase C pass 0: stage pair-rows 0..8, accumulate ----
    if (act && u < 9) {
        unsigned* dst = vreg + u * VROW;
        #pragma unroll
        for (int n = 0; n < CCH; ++n) dst[n] = rh[n];
    }
    __syncthreads();
    if (act) accum_pass<0, 9>(vreg, sh, u, aL, aH);
    __syncthreads();                         // pass-0 reads done

    // ---- phase C pass 1: stage pair-rows 9..16 (slots 0..7), accumulate ----
    if (act && u >= 9) {
        unsigned* dst = vreg + (u - 9) * VROW;
        #pragma unroll
        for (int n = 0; n < CCH; ++n) dst[n] = rh[n];
    }
    __syncthreads();
    if (act) {
        accum_pass<9, 8>(vreg, sh, u, aL, aH);

        // write S rows 2u,2u+1 = 68 contiguous floats = 17 aligned float4
        float* os = out + OFF_S + (size_t)(p0 + px) * (CCH * CCH) + 2 * u * CCH;
        #pragma unroll
        for (int q = 0; q < 17; ++q) {
            float4 v;
            v.x = (4*q+0 < 34) ? aL[4*q+0] : aH[4*q+0-34];
            v.y = (4*q+1 < 34) ? aL[4*q+1] : aH[4*q+1-34];
            v.z = (4*q+2 < 34) ? aL[4*q+2] : aH[4*q+2-34];
            v.w = (4*q+3 < 34) ? aL[4*q+3] : aH[4*q+3-34];
            *(float4*)(os + 4 * q) = v;
        }
    }
}

extern "C" void kernel_launch(void* const* d_in, const int* in_sizes, int n_in,
                              void* d_out, int out_size, void* d_ws, size_t ws_size,
                              hipStream_t stream) {
    const float* x  = (const float*)d_in[0];
    const float* W  = (const float*)d_in[1];
    const float* bv = (const float*)d_in[2];
    float* out = (float*)d_out;
    const int nblk = (NPIX + PXB - 1) / PXB;   // 2341
    hipLaunchKernelGGL(gpd_kernel, dim3(nblk), dim3(NTHR), 0, stream,
                       x, W, bv, out);
}

// Round 19
// 76.962 us; speedup vs baseline: 1.5992x; 1.0220x over previous
//
#include <hip/hip_runtime.h>

// GPDGaussian: per-pixel 629x3 conv -> (m, S=R^T diag(s) R, s)
// r19 = r13 (tied-best, 74.74us bench) + VOP3P op_sel rotations:
// the {c,s} cell from ds_read_b64 feeds v_pk ops DIRECTLY via op_sel half-
// selection (c = lo broadcast, s = hi broadcast, minus via neg_lo/neg_hi).
// Kills the ~2-4 v_mov broadcast-marshalling per rotation that accounts for
// the measured ~2x VALU-instruction overhead (6.2K cyc/px vs ~3K counted).
// Rotation = 1 ds_read_b64 + 4 pk instructions, zero movs.

#define CCH 34
#define ACH 561
#define HWPIX 4096
#define NPIX 16384
#define PXB 7                   // pixels per block
#define TPP 17                  // threads per pixel
#define NTHR 128                // 119 active in B/C
#define CSPX (141 * 8)          // cs bytes per px per chunk = 1128
#define VROW 36                 // V pair-row stride in dwords (144B)
#define VPX (17 * VROW * 4)     // 2448 B per-pixel V region
#define OFF_S 557056
#define OFF_s 19496960
#define LOG2E 1.4426950408889634f

typedef float    f32x2 __attribute__((ext_vector_type(2)));
typedef _Float16 h2    __attribute__((ext_vector_type(2)));

struct PairsT {
    short i[ACH]; short j[ACH];
    constexpr PairsT() : i(), j() {
        int p = 0;
        for (int a = 0; a < CCH - 1; ++a)
            for (int b = a + 1; b < CCH; ++b) { i[p] = (short)a; j[p] = (short)b; ++p; }
    }
};
__device__ constexpr PairsT PR{};

__device__ __forceinline__ float dot2h(h2 a, h2 b, float c) {
#if __has_builtin(__builtin_amdgcn_fdot2)
    return __builtin_amdgcn_fdot2(a, b, c, false);
#else
    return fmaf((float)a[0], (float)b[0], fmaf((float)a[1], (float)b[1], c));
#endif
}

// Givens rotation with cell={c,s} fed directly via op_sel half-selection:
//   t  = s * Rj              (s = cell.hi broadcast)
//   t2 = s * Ri
//   Ri = c * Ri + t          (c = cell.lo broadcast)
//   Rj = c * Rj - t2         (neg on the accumulator)
__device__ __forceinline__ void rot2cell(f32x2& Ri, f32x2& Rj, f32x2 cell) {
    f32x2 t1, t2;
    asm("v_pk_mul_f32 %0, %1, %2 op_sel:[1,0] op_sel_hi:[1,1]"
        : "=v"(t1) : "v"(cell), "v"(Rj));
    asm("v_pk_mul_f32 %0, %1, %2 op_sel:[1,0] op_sel_hi:[1,1]"
        : "=v"(t2) : "v"(cell), "v"(Ri));
    asm("v_pk_fma_f32 %0, %2, %0, %3 op_sel:[0,0,0] op_sel_hi:[0,1,1]"
        : "+v"(Ri) : "v"(Ri), "v"(cell), "v"(t1));
    asm("v_pk_fma_f32 %0, %2, %0, %3 op_sel:[0,0,0] op_sel_hi:[0,1,1] neg_lo:[0,0,1] neg_hi:[0,0,1]"
        : "+v"(Rj) : "v"(Rj), "v"(cell), "v"(t2));
}

template <int P0, int P1>
__device__ __forceinline__ void apply_rots(f32x2* R2, const char* csb) {
    #pragma unroll
    for (int k = P0; k < P1; ++k) {
        f32x2 cell = *(const f32x2*)(csb + (k - P0) * 8);   // {c,s} b64 read
        rot2cell(R2[PR.i[k]], R2[PR.j[k]], cell);
    }
}

__device__ __forceinline__ float2 cs_of(float wv) {
    // angle = pi*tanh(wv); HW cos/sin take revolutions: tanh(wv)/2
    float e  = __builtin_amdgcn_exp2f((2.0f * LOG2E) * wv);
    float tt = 1.0f - 2.0f * __builtin_amdgcn_rcpf(e + 1.0f);
    float rv = 0.5f * tt;
    return make_float2(__builtin_amdgcn_cosf(rv), __builtin_amdgcn_sinf(rv));
}

// one task = one pixel's angle l -> 8B {c,s} write
template <int G0, int LEN>
__device__ __forceinline__ void fill_cs(const float* __restrict__ Wm,
                                        const float* __restrict__ bvec,
                                        const float* xs, char* csbuf,
                                        int npx, int t) {
    for (int o = t; o < npx * LEN; o += NTHR) {
        int px = (int)((unsigned)o / (unsigned)LEN);
        int l  = o - px * LEN;
        int ch = 2 * CCH + G0 + l;
        float wv = fmaf(Wm[ch*3+0], xs[px*3+0],
                   fmaf(Wm[ch*3+1], xs[px*3+1], Wm[ch*3+2] * xs[px*3+2])) + bvec[ch];
        *(float2*)(csbuf + px * CSPX + l * 8) = cs_of(wv);
    }
}

__global__ __launch_bounds__(NTHR, 4) void gpd_kernel(
    const float* __restrict__ x,     // (4,3,64,64)
    const float* __restrict__ Wm,    // (629,3)
    const float* __restrict__ bvec,  // (629,)
    float* __restrict__ out)
{
    __shared__ alignas(16) char vbuf[PXB * VPX];   // 17136 B (cs 7896 overlays)
    __shared__ _Float16 lds_sh[PXB * CCH];         // s in f16
    __shared__ float xs[PXB * 3];

    const int t   = threadIdx.x;
    const int p0  = blockIdx.x * PXB;
    const int npx = min(PXB, NPIX - p0);

    // ---- stage x into LDS ----
    for (int i = t; i < npx * 3; i += NTHR) {
        int px = (int)((unsigned)i / 3u); int c = i - px * 3;
        int p = p0 + px; int b = p >> 12; int hw = p & 4095;
        xs[i] = x[(b * 3 + c) * HWPIX + hw];
    }
    __syncthreads();

    // ---- A: mean + s channels ----
    for (int o = t; o < npx * 68; o += NTHR) {
        int q = (int)((unsigned)o / 68u); int ch = o - q * 68;
        int p = p0 + q; int b = p >> 12; int hw = p & 4095;
        float wv = fmaf(Wm[ch*3+0], xs[q*3+0],
                   fmaf(Wm[ch*3+1], xs[q*3+1], Wm[ch*3+2] * xs[q*3+2])) + bvec[ch];
        if (ch < CCH) {
            out[(size_t)p * CCH + ch] = wv;                       // mean
        } else {
            float e  = __builtin_amdgcn_exp2f(-wv * LOG2E);
            float sg = __builtin_amdgcn_rcpf(1.0f + e);
            float sv = fmaf(999.999f, sg, 0.001f);                // s
            int c = ch - CCH;
            out[OFF_s + (size_t)(b * CCH + c) * HWPIX + hw] = sv;
            lds_sh[q * CCH + c] = (_Float16)sv;
        }
    }

    const int px = t / TPP;                  // pixel owned by this thread
    const int u  = t - px * TPP;             // row-pair index: rows (2u, 2u+1)
    const bool act = (px < npx) && (px < PXB);
    const char* csb = vbuf + px * CSPX;      // this pixel's cs region

    f32x2 R2[CCH];                           // R2[n] = {R[2u][n], R[2u+1][n]}
    #pragma unroll
    for (int n = 0; n < CCH; ++n) {
        R2[n][0] = (n == 2 * u)     ? 1.0f : 0.0f;
        R2[n][1] = (n == 2 * u + 1) ? 1.0f : 0.0f;
    }

    // ---- 4 chunks: fill cos/sin -> rotate ----
    fill_cs<0, 141>(Wm, bvec, xs, vbuf, npx, t);
    __syncthreads();
    if (act) apply_rots<0, 141>(R2, csb);
    __syncthreads();
    fill_cs<141, 140>(Wm, bvec, xs, vbuf, npx, t);
    __syncthreads();
    if (act) apply_rots<141, 281>(R2, csb);
    __syncthreads();
    fill_cs<281, 140>(Wm, bvec, xs, vbuf, npx, t);
    __syncthreads();
    if (act) apply_rots<281, 421>(R2, csb);
    __syncthreads();
    fill_cs<421, 140>(Wm, bvec, xs, vbuf, npx, t);
    __syncthreads();
    if (act) apply_rots<421, 561>(R2, csb);
    __syncthreads();                         // all cs reads done; V overlays

    // ---- V write: cvt_pkrtz(R2[n]) IS the f16 row-pair dword [u][n] ----
    if (act) {
        unsigned* vb = (unsigned*)(vbuf + px * VPX) + u * VROW;
        #pragma unroll
        for (int n = 0; n < CCH; ++n)
            vb[n] = __builtin_bit_cast(unsigned,
                        __builtin_amdgcn_cvt_pkrtz(R2[n][0], R2[n][1]));
    }
    __syncthreads();

    // ---- phase C: S rows 2u and 2u+1 in ONE pass (shared rr reads) ----
    if (act) {
        const unsigned* vb = (const unsigned*)(vbuf + px * VPX);
        const _Float16* sh = lds_sh + px * CCH;
        float aL[CCH], aH[CCH];
        #pragma unroll
        for (int n = 0; n < CCH; ++n) { aL[n] = 0.0f; aH[n] = 0.0f; }
        for (int mp = 0; mp < 17; ++mp) {
            const unsigned* row = vb + mp * VROW;
            h2 sh2 = *(const h2*)(sh + 2 * mp);
            h2 vkL = __builtin_bit_cast(h2, row[2 * u])     * sh2;
            h2 vkH = __builtin_bit_cast(h2, row[2 * u + 1]) * sh2;
            #pragma unroll
            for (int g = 0; g < 8; ++g) {
                uint4 rr = *(const uint4*)(row + 4 * g);
                h2 r0 = __builtin_bit_cast(h2, rr.x), r1 = __builtin_bit_cast(h2, rr.y);
                h2 r2 = __builtin_bit_cast(h2, rr.z), r3 = __builtin_bit_cast(h2, rr.w);
                aL[4*g+0] = dot2h(vkL, r0, aL[4*g+0]);  aH[4*g+0] = dot2h(vkH, r0, aH[4*g+0]);
                aL[4*g+1] = dot2h(vkL, r1, aL[4*g+1]);  aH[4*g+1] = dot2h(vkH, r1, aH[4*g+1]);
                aL[4*g+2] = dot2h(vkL, r2, aL[4*g+2]);  aH[4*g+2] = dot2h(vkH, r2, aH[4*g+2]);
                aL[4*g+3] = dot2h(vkL, r3, aL[4*g+3]);  aH[4*g+3] = dot2h(vkH, r3, aH[4*g+3]);
            }
            uint2 rr2 = *(const uint2*)(row + 32);
            h2 r32 = __builtin_bit_cast(h2, rr2.x), r33 = __builtin_bit_cast(h2, rr2.y);
            aL[32] = dot2h(vkL, r32, aL[32]);  aH[32] = dot2h(vkH, r32, aH[32]);
            aL[33] = dot2h(vkL, r33, aL[33]);  aH[33] = dot2h(vkH, r33, aH[33]);
        }
        // write rows 2u,2u+1 = 68 contiguous floats = 17 aligned float4
        float* os = out + OFF_S + (size_t)(p0 + px) * (CCH * CCH) + 2 * u * CCH;
        #pragma unroll
        for (int q = 0; q < 17; ++q) {
            float4 v;
            v.x = (4*q+0 < 34) ? aL[4*q+0] : aH[4*q+0-34];
            v.y = (4*q+1 < 34) ? aL[4*q+1] : aH[4*q+1-34];
            v.z = (4*q+2 < 34) ? aL[4*q+2] : aH[4*q+2-34];
            v.w = (4*q+3 < 34) ? aL[4*q+3] : aH[4*q+3-34];
            *(float4*)(os + 4 * q) = v;
        }
    }
}

extern "C" void kernel_launch(void* const* d_in, const int* in_sizes, int n_in,
                              void* d_out, int out_size, void* d_ws, size_t ws_size,
                              hipStream_t stream) {
    const float* x  = (const float*)d_in[0];
    const float* W  = (const float*)d_in[1];
    const float* bv = (const float*)d_in[2];
    float* out = (float*)d_out;
    const int nblk = (NPIX + PXB - 1) / PXB;   // 2341
    hipLaunchKernelGGL(gpd_kernel, dim3(nblk), dim3(NTHR), 0, stream,
                       x, W, bv, out);
}

// Round 20
// 76.248 us; speedup vs baseline: 1.6142x; 1.0094x over previous
//
#include <hip/hip_runtime.h>

// GPDGaussian: per-pixel 629x3 conv -> (m, S=R^T diag(s) R, s)
// r20 = r13/r19 base + HALVED LDS INSTRUCTION COUNT:
//  - cs read as b128 (2 {c,s} cells = 2 rotations per ds_read; 561->281
//    reads/wave). Per-CU LDS pipe was ~20us for phase B (561 reads/wave x
//    ~9.5K waves/CU) vs 16us VALU - the co-binding pipe, unoverlappable at
//    ~2 waves/SIMD due to read->use deps.
//  - phase C vk pair (row[2u],row[2u+1]) as one uint2 (b64) read.
// Zero register/structure change; CSPX padded 1128->1136 for 16B alignment.

#define CCH 34
#define ACH 561
#define HWPIX 4096
#define NPIX 16384
#define PXB 7                   // pixels per block
#define TPP 17                  // threads per pixel
#define NTHR 128                // 119 active in B/C
#define CSPX 1136               // cs bytes per px per chunk (141*8=1128, pad 16B)
#define VROW 36                 // V pair-row stride in dwords (144B)
#define VPX (17 * VROW * 4)     // 2448 B per-pixel V region
#define OFF_S 557056
#define OFF_s 19496960
#define LOG2E 1.4426950408889634f

typedef float    f32x2 __attribute__((ext_vector_type(2)));
typedef float    f32x4 __attribute__((ext_vector_type(4)));
typedef _Float16 h2    __attribute__((ext_vector_type(2)));

struct PairsT {
    short i[ACH]; short j[ACH];
    constexpr PairsT() : i(), j() {
        int p = 0;
        for (int a = 0; a < CCH - 1; ++a)
            for (int b = a + 1; b < CCH; ++b) { i[p] = (short)a; j[p] = (short)b; ++p; }
    }
};
__device__ constexpr PairsT PR{};

__device__ __forceinline__ float dot2h(h2 a, h2 b, float c) {
#if __has_builtin(__builtin_amdgcn_fdot2)
    return __builtin_amdgcn_fdot2(a, b, c, false);
#else
    return fmaf((float)a[0], (float)b[0], fmaf((float)a[1], (float)b[1], c));
#endif
}

// Givens rotation with cell={c,s} fed directly via op_sel half-selection
// (r19-verified): t=s*Rj; t2=s*Ri; Ri=c*Ri+t; Rj=c*Rj-t2.
__device__ __forceinline__ void rot2cell(f32x2& Ri, f32x2& Rj, f32x2 cell) {
    f32x2 t1, t2;
    asm("v_pk_mul_f32 %0, %1, %2 op_sel:[1,0] op_sel_hi:[1,1]"
        : "=v"(t1) : "v"(cell), "v"(Rj));
    asm("v_pk_mul_f32 %0, %1, %2 op_sel:[1,0] op_sel_hi:[1,1]"
        : "=v"(t2) : "v"(cell), "v"(Ri));
    asm("v_pk_fma_f32 %0, %2, %0, %3 op_sel:[0,0,0] op_sel_hi:[0,1,1]"
        : "+v"(Ri) : "v"(Ri), "v"(cell), "v"(t1));
    asm("v_pk_fma_f32 %0, %2, %0, %3 op_sel:[0,0,0] op_sel_hi:[0,1,1] neg_lo:[0,0,1] neg_hi:[0,0,1]"
        : "+v"(Rj) : "v"(Rj), "v"(cell), "v"(t2));
}

template <int P0, int P1>
__device__ __forceinline__ void apply_rots(f32x2* R2, const char* csb) {
    constexpr int N = P1 - P0;
    #pragma unroll
    for (int k = 0; k + 1 < N; k += 2) {
        f32x4 cc = *(const f32x4*)(csb + k * 8);        // cells k, k+1 (b128)
        f32x2 cA = __builtin_shufflevector(cc, cc, 0, 1);  // register aliases,
        f32x2 cB = __builtin_shufflevector(cc, cc, 2, 3);  // no movs
        rot2cell(R2[PR.i[P0 + k]],     R2[PR.j[P0 + k]],     cA);
        rot2cell(R2[PR.i[P0 + k + 1]], R2[PR.j[P0 + k + 1]], cB);
    }
    if constexpr (N & 1) {
        f32x2 cell = *(const f32x2*)(csb + (N - 1) * 8);
        rot2cell(R2[PR.i[P1 - 1]], R2[PR.j[P1 - 1]], cell);
    }
}

__device__ __forceinline__ float2 cs_of(float wv) {
    // angle = pi*tanh(wv); HW cos/sin take revolutions: tanh(wv)/2
    float e  = __builtin_amdgcn_exp2f((2.0f * LOG2E) * wv);
    float tt = 1.0f - 2.0f * __builtin_amdgcn_rcpf(e + 1.0f);
    float rv = 0.5f * tt;
    return make_float2(__builtin_amdgcn_cosf(rv), __builtin_amdgcn_sinf(rv));
}

// one task = one pixel's angle l -> 8B {c,s} write
template <int G0, int LEN>
__device__ __forceinline__ void fill_cs(const float* __restrict__ Wm,
                                        const float* __restrict__ bvec,
                                        const float* xs, char* csbuf,
                                        int npx, int t) {
    for (int o = t; o < npx * LEN; o += NTHR) {
        int px = (int)((unsigned)o / (unsigned)LEN);
        int l  = o - px * LEN;
        int ch = 2 * CCH + G0 + l;
        float wv = fmaf(Wm[ch*3+0], xs[px*3+0],
                   fmaf(Wm[ch*3+1], xs[px*3+1], Wm[ch*3+2] * xs[px*3+2])) + bvec[ch];
        *(float2*)(csbuf + px * CSPX + l * 8) = cs_of(wv);
    }
}

__global__ __launch_bounds__(NTHR, 4) void gpd_kernel(
    const float* __restrict__ x,     // (4,3,64,64)
    const float* __restrict__ Wm,    // (629,3)
    const float* __restrict__ bvec,  // (629,)
    float* __restrict__ out)
{
    __shared__ alignas(16) char vbuf[PXB * VPX];   // 17136 B (cs 7952 overlays)
    __shared__ _Float16 lds_sh[PXB * CCH];         // s in f16
    __shared__ float xs[PXB * 3];

    const int t   = threadIdx.x;
    const int p0  = blockIdx.x * PXB;
    const int npx = min(PXB, NPIX - p0);

    // ---- stage x into LDS ----
    for (int i = t; i < npx * 3; i += NTHR) {
        int px = (int)((unsigned)i / 3u); int c = i - px * 3;
        int p = p0 + px; int b = p >> 12; int hw = p & 4095;
        xs[i] = x[(b * 3 + c) * HWPIX + hw];
    }
    __syncthreads();

    // ---- A: mean + s channels ----
    for (int o = t; o < npx * 68; o += NTHR) {
        int q = (int)((unsigned)o / 68u); int ch = o - q * 68;
        int p = p0 + q; int b = p >> 12; int hw = p & 4095;
        float wv = fmaf(Wm[ch*3+0], xs[q*3+0],
                   fmaf(Wm[ch*3+1], xs[q*3+1], Wm[ch*3+2] * xs[q*3+2])) + bvec[ch];
        if (ch < CCH) {
            out[(size_t)p * CCH + ch] = wv;                       // mean
        } else {
            float e  = __builtin_amdgcn_exp2f(-wv * LOG2E);
            float sg = __builtin_amdgcn_rcpf(1.0f + e);
            float sv = fmaf(999.999f, sg, 0.001f);                // s
            int c = ch - CCH;
            out[OFF_s + (size_t)(b * CCH + c) * HWPIX + hw] = sv;
            lds_sh[q * CCH + c] = (_Float16)sv;
        }
    }

    const int px = t / TPP;                  // pixel owned by this thread
    const int u  = t - px * TPP;             // row-pair index: rows (2u, 2u+1)
    const bool act = (px < npx) && (px < PXB);
    const char* csb = vbuf + px * CSPX;      // this pixel's cs region (16B-aligned)

    f32x2 R2[CCH];                           // R2[n] = {R[2u][n], R[2u+1][n]}
    #pragma unroll
    for (int n = 0; n < CCH; ++n) {
        R2[n][0] = (n == 2 * u)     ? 1.0f : 0.0f;
        R2[n][1] = (n == 2 * u + 1) ? 1.0f : 0.0f;
    }

    // ---- 4 chunks: fill cos/sin -> rotate ----
    fill_cs<0, 141>(Wm, bvec, xs, vbuf, npx, t);
    __syncthreads();
    if (act) apply_rots<0, 141>(R2, csb);
    __syncthreads();
    fill_cs<141, 140>(Wm, bvec, xs, vbuf, npx, t);
    __syncthreads();
    if (act) apply_rots<141, 281>(R2, csb);
    __syncthreads();
    fill_cs<281, 140>(Wm, bvec, xs, vbuf, npx, t);
    __syncthreads();
    if (act) apply_rots<281, 421>(R2, csb);
    __syncthreads();
    fill_cs<421, 140>(Wm, bvec, xs, vbuf, npx, t);
    __syncthreads();
    if (act) apply_rots<421, 561>(R2, csb);
    __syncthreads();                         // all cs reads done; V overlays

    // ---- V write: cvt_pkrtz(R2[n]) IS the f16 row-pair dword [u][n] ----
    if (act) {
        unsigned* vb = (unsigned*)(vbuf + px * VPX) + u * VROW;
        #pragma unroll
        for (int n = 0; n < CCH; ++n)
            vb[n] = __builtin_bit_cast(unsigned,
                        __builtin_amdgcn_cvt_pkrtz(R2[n][0], R2[n][1]));
    }
    __syncthreads();

    // ---- phase C: S rows 2u and 2u+1 in ONE pass (shared rr reads) ----
    if (act) {
        const unsigned* vb = (const unsigned*)(vbuf + px * VPX);
        const _Float16* sh = lds_sh + px * CCH;
        float aL[CCH], aH[CCH];
        #pragma unroll
        for (int n = 0; n < CCH; ++n) { aL[n] = 0.0f; aH[n] = 0.0f; }
        for (int mp = 0; mp < 17; ++mp) {
            const unsigned* row = vb + mp * VROW;
            h2 sh2 = *(const h2*)(sh + 2 * mp);
            uint2 vk2 = *(const uint2*)(row + 2 * u);   // rows 2u,2u+1: one b64
            h2 vkL = __builtin_bit_cast(h2, vk2.x) * sh2;
            h2 vkH = __builtin_bit_cast(h2, vk2.y) * sh2;
            #pragma unroll
            for (int g = 0; g < 8; ++g) {
                uint4 rr = *(const uint4*)(row + 4 * g);
                h2 r0 = __builtin_bit_cast(h2, rr.x), r1 = __builtin_bit_cast(h2, rr.y);
                h2 r2 = __builtin_bit_cast(h2, rr.z), r3 = __builtin_bit_cast(h2, rr.w);
                aL[4*g+0] = dot2h(vkL, r0, aL[4*g+0]);  aH[4*g+0] = dot2h(vkH, r0, aH[4*g+0]);
                aL[4*g+1] = dot2h(vkL, r1, aL[4*g+1]);  aH[4*g+1] = dot2h(vkH, r1, aH[4*g+1]);
                aL[4*g+2] = dot2h(vkL, r2, aL[4*g+2]);  aH[4*g+2] = dot2h(vkH, r2, aH[4*g+2]);
                aL[4*g+3] = dot2h(vkL, r3, aL[4*g+3]);  aH[4*g+3] = dot2h(vkH, r3, aH[4*g+3]);
            }
            uint2 rr2 = *(const uint2*)(row + 32);
            h2 r32 = __builtin_bit_cast(h2, rr2.x), r33 = __builtin_bit_cast(h2, rr2.y);
            aL[32] = dot2h(vkL, r32, aL[32]);  aH[32] = dot2h(vkH, r32, aH[32]);
            aL[33] = dot2h(vkL, r33, aL[33]);  aH[33] = dot2h(vkH, r33, aH[33]);
        }
        // write rows 2u,2u+1 = 68 contiguous floats = 17 aligned float4
        float* os = out + OFF_S + (size_t)(p0 + px) * (CCH * CCH) + 2 * u * CCH;
        #pragma unroll
        for (int q = 0; q < 17; ++q) {
            float4 v;
            v.x = (4*q+0 < 34) ? aL[4*q+0] : aH[4*q+0-34];
            v.y = (4*q+1 < 34) ? aL[4*q+1] : aH[4*q+1-34];
            v.z = (4*q+2 < 34) ? aL[4*q+2] : aH[4*q+2-34];
            v.w = (4*q+3 < 34) ? aL[4*q+3] : aH[4*q+3-34];
            *(float4*)(os + 4 * q) = v;
        }
    }
}

extern "C" void kernel_launch(void* const* d_in, const int* in_sizes, int n_in,
                              void* d_out, int out_size, void* d_ws, size_t ws_size,
                              hipStream_t stream) {
    const float* x  = (const float*)d_in[0];
    const float* W  = (const float*)d_in[1];
    const float* bv = (const float*)d_in[2];
    float* out = (float*)d_out;
    const int nblk = (NPIX + PXB - 1) / PXB;   // 2341
    hipLaunchKernelGGL(gpd_kernel, dim3(nblk), dim3(NTHR), 0, stream,
                       x, W, bv, out);
}